// Round 1
// baseline (4741.525 us; speedup 1.0000x reference)
//
#include <hip/hip_runtime.h>

// Problem constants (match reference setup_inputs)
#define BB 16
#define NN 2048
#define EE 32768
#define DD 256
#define RR 8
#define LL 2

// ---------------------------------------------------------------------------
// gather: x0[bb, n, :] = emb[nodes[b0+bb, n], :]   (float4 per thread)
// ---------------------------------------------------------------------------
__global__ __launch_bounds__(256) void gather_k(const int* __restrict__ nodes,
                                                const float* __restrict__ emb,
                                                float* __restrict__ x0,
                                                int b0, int bc)
{
    int t = blockIdx.x * 256 + threadIdx.x;
    int lane = t & 63;          // which float4 of the 256-float row
    int row = t >> 6;           // (bb, n) flattened
    if (row >= bc * NN) return;
    int bb = row / NN;
    int n  = row - bb * NN;
    int v  = nodes[(size_t)(b0 + bb) * NN + n];
    float4 val = *((const float4*)(emb + (size_t)v * DD) + lane);
    *((float4*)(x0 + (size_t)row * DD) + lane) = val;
}

// ---------------------------------------------------------------------------
// deg: deg[bb, dst] += 1 per edge (dst is layer-independent; run once/chunk)
// ---------------------------------------------------------------------------
__global__ __launch_bounds__(256) void deg_k(const int* __restrict__ edges,
                                             float* __restrict__ deg,
                                             int b0, int bc)
{
    int t = blockIdx.x * 256 + threadIdx.x;
    if (t >= bc * EE) return;
    int bb = t / EE;
    int e  = t - bb * EE;
    int dst = edges[(size_t)(b0 + bb) * 2 * EE + EE + e];
    atomicAdd(&deg[(size_t)bb * NN + dst], 1.0f);
}

// ---------------------------------------------------------------------------
// scatter: s[bb, type_e, dst_e, :] += xin[bb, src_e, :]
// one wave (64 lanes) per edge, 4 floats (1 float4 read, 4 atomics) per lane
// ---------------------------------------------------------------------------
__global__ __launch_bounds__(256) void scatter_k(const int* __restrict__ edges,
                                                 const int* __restrict__ types,
                                                 const float* __restrict__ xin,
                                                 float* __restrict__ s,
                                                 int b0, int bc)
{
    int t = blockIdx.x * 256 + threadIdx.x;
    int lane = t & 63;
    int er = t >> 6;            // edge index within chunk
    if (er >= bc * EE) return;
    int bb = er / EE;
    int e  = er - bb * EE;
    const int* eb = edges + (size_t)(b0 + bb) * 2 * EE;
    int src = eb[e];
    int dst = eb[EE + e];
    int r   = types[(size_t)(b0 + bb) * EE + e];
    float4 v = *((const float4*)(xin + ((size_t)bb * NN + src) * DD) + lane);
    float* sp = s + ((((size_t)bb * RR + r) * NN + dst) * DD) + lane * 4;
    atomicAdd(sp + 0, v.x);
    atomicAdd(sp + 1, v.y);
    atomicAdd(sp + 2, v.z);
    atomicAdd(sp + 3, v.w);
}

// ---------------------------------------------------------------------------
// fused GEMM: out[bb,m,n] = relu?( (Σ_r s[bb,r,m,:] @ W[r]) * invdeg[bb,m]
//                                  + xin[bb,m,:] @ Wroot + bias[n] )
// 64x64 output tile per block, 256 threads, 4x4 acc per thread, BK=16
// ---------------------------------------------------------------------------
__global__ __launch_bounds__(256) void rgcn_gemm(const float* __restrict__ sB,
                                                 const float* __restrict__ xin,
                                                 const float* __restrict__ Wl,
                                                 const float* __restrict__ Wr,
                                                 const float* __restrict__ bias,
                                                 const float* __restrict__ deg,
                                                 float* __restrict__ outp,
                                                 int relu)
{
    __shared__ __align__(16) float Ast[16][68];   // [k][m], padded: stride 68 (272B, 16B-aligned)
    __shared__ __align__(16) float Bs[16][64];    // [k][n]

    int bb = blockIdx.z;
    int m0 = blockIdx.x * 64;
    int n0 = blockIdx.y * 64;
    int tid = threadIdx.x;
    int tx = tid & 15;          // output col group
    int ty = tid >> 4;          // output row group

    const float* sBat = sB  + (size_t)bb * RR * NN * DD;
    const float* xb   = xin + (size_t)bb * NN * DD;
    const float* degb = deg + (size_t)bb * NN;

    float acc[4][4] = {};

    // loader coords
    int lr = tid >> 2;          // A row 0..63
    int lc = (tid & 3) * 4;     // A col group 0,4,8,12
    int brr = tid >> 4;         // B row 0..15
    int bcol = (tid & 15) * 4;  // B col group

    for (int seg = 0; seg <= RR; ++seg) {
        const float* Ab;
        const float* Bb;
        if (seg < RR) {
            Ab = sBat + (size_t)seg * NN * DD;
            Bb = Wl + (size_t)seg * DD * DD;
        } else {
            // aggregation done: normalize by degree before adding root term
            #pragma unroll
            for (int i = 0; i < 4; ++i) {
                float dg = degb[m0 + ty * 4 + i];
                float inv = 1.0f / fmaxf(dg, 1.0f);
                #pragma unroll
                for (int j = 0; j < 4; ++j) acc[i][j] *= inv;
            }
            Ab = xb;
            Bb = Wr;
        }
        for (int kt = 0; kt < DD / 16; ++kt) {
            int k0 = kt * 16;
            float4 av = *(const float4*)(Ab + (size_t)(m0 + lr) * DD + k0 + lc);
            float4 bv = *(const float4*)(Bb + (size_t)(k0 + brr) * DD + n0 + bcol);
            __syncthreads();
            Ast[lc + 0][lr] = av.x;
            Ast[lc + 1][lr] = av.y;
            Ast[lc + 2][lr] = av.z;
            Ast[lc + 3][lr] = av.w;
            *(float4*)&Bs[brr][bcol] = bv;
            __syncthreads();
            #pragma unroll
            for (int kk = 0; kk < 16; ++kk) {
                float a[4], b[4];
                *(float4*)a = *(const float4*)&Ast[kk][ty * 4];
                *(float4*)b = *(const float4*)&Bs[kk][tx * 4];
                #pragma unroll
                for (int i = 0; i < 4; ++i)
                    #pragma unroll
                    for (int j = 0; j < 4; ++j)
                        acc[i][j] += a[i] * b[j];
            }
        }
    }

    // epilogue: bias (+ relu), coalesced float4 stores
    #pragma unroll
    for (int i = 0; i < 4; ++i) {
        int m = m0 + ty * 4 + i;
        float o[4];
        #pragma unroll
        for (int j = 0; j < 4; ++j) {
            float v = acc[i][j] + bias[n0 + tx * 4 + j];
            if (relu) v = fmaxf(v, 0.0f);
            o[j] = v;
        }
        *(float4*)(outp + ((size_t)bb * NN + m) * DD + n0 + tx * 4) = *(float4*)o;
    }
}

// ---------------------------------------------------------------------------
extern "C" void kernel_launch(void* const* d_in, const int* in_sizes, int n_in,
                              void* d_out, int out_size, void* d_ws, size_t ws_size,
                              hipStream_t stream)
{
    const int*   nodes = (const int*)d_in[0];
    const int*   edges = (const int*)d_in[1];
    const int*   types = (const int*)d_in[2];
    const float* emb   = (const float*)d_in[3];
    const float* W     = (const float*)d_in[4];
    const float* Wroot = (const float*)d_in[5];
    const float* bias  = (const float*)d_in[6];
    float* out = (float*)d_out;

    // per-batch workspace: s (R*N*D) + x0 (N*D) + x1 (N*D) + deg (N) floats
    const size_t perBatchFloats = (size_t)RR * NN * DD + 2 * (size_t)NN * DD + NN;
    int BC = (int)(ws_size / (perBatchFloats * sizeof(float)));
    if (BC > BB) BC = BB;
    if (BC < 1) BC = 1;

    float* sBuf = (float*)d_ws;
    float* x0   = sBuf + (size_t)BC * RR * NN * DD;
    float* x1   = x0 + (size_t)BC * NN * DD;
    float* deg  = x1 + (size_t)BC * NN * DD;

    for (int b0 = 0; b0 < BB; b0 += BC) {
        int bc = BB - b0 < BC ? BB - b0 : BC;

        hipMemsetAsync(deg, 0, (size_t)bc * NN * sizeof(float), stream);
        gather_k<<<bc * 512, 256, 0, stream>>>(nodes, emb, x0, b0, bc);
        deg_k<<<bc * 128, 256, 0, stream>>>(edges, deg, b0, bc);

        for (int l = 0; l < LL; ++l) {
            hipMemsetAsync(sBuf, 0, (size_t)bc * RR * NN * DD * sizeof(float), stream);
            const float* xin = (l == 0) ? x0 : x1;
            scatter_k<<<bc * 8192, 256, 0, stream>>>(edges, types, xin, sBuf, b0, bc);
            float* outp = (l == 0) ? x1 : (out + (size_t)b0 * NN * DD);
            rgcn_gemm<<<dim3(NN / 64, DD / 64, bc), 256, 0, stream>>>(
                sBuf, xin,
                W + (size_t)l * RR * DD * DD,
                Wroot + (size_t)l * DD * DD,
                bias + (size_t)l * DD,
                deg, outp, (l == 0) ? 1 : 0);
        }
    }
}

// Round 2
// 1451.627 us; speedup vs baseline: 3.2664x; 3.2664x over previous
//
#include <hip/hip_runtime.h>

// Problem constants (match reference setup_inputs)
#define BB 16
#define NN 2048
#define EE 32768
#define DD 256
#define RR 8
#define LL 2
#define BUCKETS (RR * NN)   // 16384 buckets per batch (power of 2)

// ---------------------------------------------------------------------------
// gather: x0[bb, n, :] = emb[nodes[b0+bb, n], :]   (float4 per thread)
// ---------------------------------------------------------------------------
__global__ __launch_bounds__(256) void gather_k(const int* __restrict__ nodes,
                                                const float* __restrict__ emb,
                                                float* __restrict__ x0,
                                                int b0, int bc)
{
    int t = blockIdx.x * 256 + threadIdx.x;
    int lane = t & 63;          // which float4 of the 256-float row
    int row = t >> 6;           // (bb, n) flattened
    if (row >= bc * NN) return;
    int bb = row / NN;
    int n  = row - bb * NN;
    int v  = nodes[(size_t)(b0 + bb) * NN + n];
    float4 val = *((const float4*)(emb + (size_t)v * DD) + lane);
    *((float4*)(x0 + (size_t)row * DD) + lane) = val;
}

// ---------------------------------------------------------------------------
// CSR build step 1: counts[bb][r][dst] += 1 per edge (int atomics, cheap)
// ---------------------------------------------------------------------------
__global__ __launch_bounds__(256) void count_k(const int* __restrict__ edges,
                                               const int* __restrict__ types,
                                               int* __restrict__ counts,
                                               int b0, int bc)
{
    int t = blockIdx.x * 256 + threadIdx.x;
    if (t >= bc * EE) return;
    int bb = t / EE;
    int e  = t - bb * EE;
    const int* eb = edges + (size_t)(b0 + bb) * 2 * EE;
    int dst = eb[EE + e];
    int r   = types[(size_t)(b0 + bb) * EE + e];
    atomicAdd(&counts[((size_t)bb * RR + r) * NN + dst], 1);
}

// ---------------------------------------------------------------------------
// CSR build step 2: exclusive scan of counts per batch (16384 entries).
// One block of 256 threads per batch; each thread owns 64 consecutive buckets.
// Writes offsets AND cursor (cursor is consumed by permute_k's atomics).
// ---------------------------------------------------------------------------
__global__ __launch_bounds__(256) void scan_k(const int* __restrict__ counts,
                                              int* __restrict__ offsets,
                                              int* __restrict__ cursor)
{
    int bb = blockIdx.x;
    int tid = threadIdx.x;
    size_t base = (size_t)bb * BUCKETS;
    __shared__ int sums[256];

    int tot = 0;
    #pragma unroll 4
    for (int i = 0; i < 64; ++i) tot += counts[base + tid * 64 + i];
    sums[tid] = tot;
    __syncthreads();
    // Hillis-Steele inclusive scan
    for (int off = 1; off < 256; off <<= 1) {
        int v = (tid >= off) ? sums[tid - off] : 0;
        __syncthreads();
        sums[tid] += v;
        __syncthreads();
    }
    int run = sums[tid] - tot;   // exclusive prefix of this thread's chunk
    for (int i = 0; i < 64; ++i) {
        size_t idx = base + tid * 64 + i;
        offsets[idx] = run;
        cursor[idx]  = run;
        run += counts[idx];
    }
}

// ---------------------------------------------------------------------------
// deg[bb][n] = sum_r counts[bb][r][n]  (atomic-free, replaces deg_k)
// ---------------------------------------------------------------------------
__global__ __launch_bounds__(256) void deg_from_counts(const int* __restrict__ counts,
                                                       float* __restrict__ deg,
                                                       int bc)
{
    int t = blockIdx.x * 256 + threadIdx.x;
    if (t >= bc * NN) return;
    int bb = t / NN;
    int n  = t - bb * NN;
    int d = 0;
    #pragma unroll
    for (int r = 0; r < RR; ++r)
        d += counts[((size_t)bb * RR + r) * NN + n];
    deg[t] = (float)d;
}

// ---------------------------------------------------------------------------
// CSR build step 3: place each edge's src into its bucket slot
// ---------------------------------------------------------------------------
__global__ __launch_bounds__(256) void permute_k(const int* __restrict__ edges,
                                                 const int* __restrict__ types,
                                                 int* __restrict__ cursor,
                                                 int* __restrict__ edgeSrc,
                                                 int b0, int bc)
{
    int t = blockIdx.x * 256 + threadIdx.x;
    if (t >= bc * EE) return;
    int bb = t / EE;
    int e  = t - bb * EE;
    const int* eb = edges + (size_t)(b0 + bb) * 2 * EE;
    int src = eb[e];
    int dst = eb[EE + e];
    int r   = types[(size_t)(b0 + bb) * EE + e];
    int pos = atomicAdd(&cursor[((size_t)bb * RR + r) * NN + dst], 1);
    edgeSrc[(size_t)bb * EE + pos] = src;
}

// ---------------------------------------------------------------------------
// aggregation (atomic-free): one wave per bucket (bb, r, dst):
//   s[bucket, :] = sum over bucket's edges of xin[bb, src, :]
// Each of 64 lanes owns one float4 of the 256-float row. Empty buckets
// write zeros (so no sBuf memset is needed).
// ---------------------------------------------------------------------------
__global__ __launch_bounds__(256) void agg_k(const int* __restrict__ offsets,
                                             const int* __restrict__ counts,
                                             const int* __restrict__ edgeSrc,
                                             const float* __restrict__ xin,
                                             float* __restrict__ s,
                                             int bc)
{
    int g = blockIdx.x * 4 + (threadIdx.x >> 6);   // bucket id
    int lane = threadIdx.x & 63;
    if (g >= bc * BUCKETS) return;
    int bb  = g >> 14;            // BUCKETS = 2^14
    int start = offsets[g];
    int cnt   = counts[g];
    const float* xb = xin + (size_t)bb * NN * DD;
    const int* es   = edgeSrc + (size_t)bb * EE;
    float4 acc = make_float4(0.f, 0.f, 0.f, 0.f);
    for (int j = 0; j < cnt; ++j) {
        int src = es[start + j];
        float4 v = *((const float4*)(xb + (size_t)src * DD) + lane);
        acc.x += v.x; acc.y += v.y; acc.z += v.z; acc.w += v.w;
    }
    *((float4*)(s + (size_t)g * DD) + lane) = acc;
}

// ---------------------------------------------------------------------------
// fused GEMM: out[bb,m,n] = relu?( (Σ_r s[bb,r,m,:] @ W[r]) * invdeg[bb,m]
//                                  + xin[bb,m,:] @ Wroot + bias[n] )
// 64x64 output tile per block, 256 threads, 4x4 acc per thread, BK=16
// ---------------------------------------------------------------------------
__global__ __launch_bounds__(256) void rgcn_gemm(const float* __restrict__ sB,
                                                 const float* __restrict__ xin,
                                                 const float* __restrict__ Wl,
                                                 const float* __restrict__ Wr,
                                                 const float* __restrict__ bias,
                                                 const float* __restrict__ deg,
                                                 float* __restrict__ outp,
                                                 int relu)
{
    __shared__ __align__(16) float Ast[16][68];   // [k][m], padded
    __shared__ __align__(16) float Bs[16][64];    // [k][n]

    int bb = blockIdx.z;
    int m0 = blockIdx.x * 64;
    int n0 = blockIdx.y * 64;
    int tid = threadIdx.x;
    int tx = tid & 15;          // output col group
    int ty = tid >> 4;          // output row group

    const float* sBat = sB  + (size_t)bb * RR * NN * DD;
    const float* xb   = xin + (size_t)bb * NN * DD;
    const float* degb = deg + (size_t)bb * NN;

    float acc[4][4] = {};

    int lr = tid >> 2;          // A row 0..63
    int lc = (tid & 3) * 4;     // A col group 0,4,8,12
    int brr = tid >> 4;         // B row 0..15
    int bcol = (tid & 15) * 4;  // B col group

    for (int seg = 0; seg <= RR; ++seg) {
        const float* Ab;
        const float* Bb;
        if (seg < RR) {
            Ab = sBat + (size_t)seg * NN * DD;
            Bb = Wl + (size_t)seg * DD * DD;
        } else {
            // aggregation done: normalize by degree before adding root term
            #pragma unroll
            for (int i = 0; i < 4; ++i) {
                float dg = degb[m0 + ty * 4 + i];
                float inv = 1.0f / fmaxf(dg, 1.0f);
                #pragma unroll
                for (int j = 0; j < 4; ++j) acc[i][j] *= inv;
            }
            Ab = xb;
            Bb = Wr;
        }
        for (int kt = 0; kt < DD / 16; ++kt) {
            int k0 = kt * 16;
            float4 av = *(const float4*)(Ab + (size_t)(m0 + lr) * DD + k0 + lc);
            float4 bv = *(const float4*)(Bb + (size_t)(k0 + brr) * DD + n0 + bcol);
            __syncthreads();
            Ast[lc + 0][lr] = av.x;
            Ast[lc + 1][lr] = av.y;
            Ast[lc + 2][lr] = av.z;
            Ast[lc + 3][lr] = av.w;
            *(float4*)&Bs[brr][bcol] = bv;
            __syncthreads();
            #pragma unroll
            for (int kk = 0; kk < 16; ++kk) {
                float a[4], b[4];
                *(float4*)a = *(const float4*)&Ast[kk][ty * 4];
                *(float4*)b = *(const float4*)&Bs[kk][tx * 4];
                #pragma unroll
                for (int i = 0; i < 4; ++i)
                    #pragma unroll
                    for (int j = 0; j < 4; ++j)
                        acc[i][j] += a[i] * b[j];
            }
        }
    }

    // epilogue: bias (+ relu), coalesced float4 stores
    #pragma unroll
    for (int i = 0; i < 4; ++i) {
        int m = m0 + ty * 4 + i;
        float o[4];
        #pragma unroll
        for (int j = 0; j < 4; ++j) {
            float v = acc[i][j] + bias[n0 + tx * 4 + j];
            if (relu) v = fmaxf(v, 0.0f);
            o[j] = v;
        }
        *(float4*)(outp + ((size_t)bb * NN + m) * DD + n0 + tx * 4) = *(float4*)o;
    }
}

// ---------------------------------------------------------------------------
extern "C" void kernel_launch(void* const* d_in, const int* in_sizes, int n_in,
                              void* d_out, int out_size, void* d_ws, size_t ws_size,
                              hipStream_t stream)
{
    const int*   nodes = (const int*)d_in[0];
    const int*   edges = (const int*)d_in[1];
    const int*   types = (const int*)d_in[2];
    const float* emb   = (const float*)d_in[3];
    const float* W     = (const float*)d_in[4];
    const float* Wroot = (const float*)d_in[5];
    const float* bias  = (const float*)d_in[6];
    float* out = (float*)d_out;

    // per-batch workspace (bytes):
    //   sBuf R*N*D f32 + x0 N*D + x1 N*D + deg N + counts/offsets/cursor 3*R*N int + edgeSrc E int
    const size_t perBatchBytes =
        ((size_t)RR * NN * DD + 2 * (size_t)NN * DD + NN) * sizeof(float) +
        (3 * (size_t)BUCKETS + EE) * sizeof(int);
    int BC = (int)(ws_size / perBatchBytes);
    if (BC > BB) BC = BB;
    if (BC < 1) BC = 1;

    float* sBuf = (float*)d_ws;
    float* x0   = sBuf + (size_t)BC * RR * NN * DD;
    float* x1   = x0 + (size_t)BC * NN * DD;
    float* deg  = x1 + (size_t)BC * NN * DD;
    int* counts  = (int*)(deg + (size_t)BC * NN);
    int* offsets = counts + (size_t)BC * BUCKETS;
    int* cursor  = offsets + (size_t)BC * BUCKETS;
    int* edgeSrc = cursor + (size_t)BC * BUCKETS;

    for (int b0 = 0; b0 < BB; b0 += BC) {
        int bc = BB - b0 < BC ? BB - b0 : BC;

        // ---- CSR build (once per chunk; dst/type are layer-invariant) ----
        hipMemsetAsync(counts, 0, (size_t)bc * BUCKETS * sizeof(int), stream);
        gather_k<<<bc * 512, 256, 0, stream>>>(nodes, emb, x0, b0, bc);
        count_k<<<bc * (EE / 256), 256, 0, stream>>>(edges, types, counts, b0, bc);
        scan_k<<<bc, 256, 0, stream>>>(counts, offsets, cursor);
        deg_from_counts<<<bc * (NN / 256), 256, 0, stream>>>(counts, deg, bc);
        permute_k<<<bc * (EE / 256), 256, 0, stream>>>(edges, types, cursor, edgeSrc, b0, bc);

        for (int l = 0; l < LL; ++l) {
            const float* xin = (l == 0) ? x0 : x1;
            agg_k<<<bc * (BUCKETS / 4), 256, 0, stream>>>(offsets, counts, edgeSrc, xin, sBuf, bc);
            float* outp = (l == 0) ? x1 : (out + (size_t)b0 * NN * DD);
            rgcn_gemm<<<dim3(NN / 64, DD / 64, bc), 256, 0, stream>>>(
                sBuf, xin,
                W + (size_t)l * RR * DD * DD,
                Wroot + (size_t)l * DD * DD,
                bias + (size_t)l * DD,
                deg, outp, (l == 0) ? 1 : 0);
        }
    }
}

// Round 3
// 460.867 us; speedup vs baseline: 10.2883x; 3.1498x over previous
//
#include <hip/hip_runtime.h>

// Problem constants (match reference setup_inputs)
#define BB 16
#define NN 2048
#define EE 32768
#define DD 256
#define RR 8
#define LL 2
#define BUCKETS (RR * NN)   // 16384 buckets per batch (power of 2)

typedef unsigned short u16;
typedef __attribute__((__ext_vector_type__(8))) __bf16 bfx8;   // MFMA A/B frag (4 VGPR)
typedef __attribute__((__ext_vector_type__(16))) float fx16;   // MFMA acc (16 VGPR)

__device__ __forceinline__ float bf2f(u16 s) {
    union { unsigned u; float f; } x; x.u = ((unsigned)s) << 16; return x.f;
}
__device__ __forceinline__ u16 f2bf(float f) {
    union { float f; unsigned u; } x; x.f = f;
    unsigned u = x.u;
    return (u16)((u + 0x7FFFu + ((u >> 16) & 1u)) >> 16);   // RNE
}
// async global->LDS, 16B per lane; lds base must be wave-uniform
__device__ __forceinline__ void async16(const void* g, void* l) {
    __builtin_amdgcn_global_load_lds(
        (const __attribute__((address_space(1))) unsigned char*)g,
        (__attribute__((address_space(3))) unsigned char*)l, 16, 0, 0);
}

// ---------------------------------------------------------------------------
// gather: x0[bb, n, :] = bf16(emb[nodes[b0+bb, n], :])
// ---------------------------------------------------------------------------
__global__ __launch_bounds__(256) void gather_k(const int* __restrict__ nodes,
                                                const float* __restrict__ emb,
                                                u16* __restrict__ x0,
                                                int b0, int bc)
{
    int t = blockIdx.x * 256 + threadIdx.x;
    int lane = t & 63;          // which float4 of the 256-float row
    int row = t >> 6;           // (bb, n) flattened
    if (row >= bc * NN) return;
    int bb = row / NN;
    int n  = row - bb * NN;
    int v  = nodes[(size_t)(b0 + bb) * NN + n];
    float4 val = *((const float4*)(emb + (size_t)v * DD) + lane);
    ushort4 o;
    o.x = f2bf(val.x); o.y = f2bf(val.y); o.z = f2bf(val.z); o.w = f2bf(val.w);
    *((ushort4*)(x0 + (size_t)row * DD) + lane) = o;
}

// ---------------------------------------------------------------------------
// weight prep: Wt[l*9+seg][n][k] = bf16(W[l][seg][k][n]) (seg<8) / Wroot (seg=8)
// 64x64 LDS tile transpose; grid = (16 tiles, L*9)
// ---------------------------------------------------------------------------
__global__ __launch_bounds__(256) void wt_k(const float* __restrict__ W,
                                            const float* __restrict__ Wroot,
                                            u16* __restrict__ Wt)
{
    __shared__ float tl[64][65];
    int ls = blockIdx.y;                 // l*9 + seg
    int l = ls / 9, seg = ls - l * 9;
    int kt = (blockIdx.x >> 2) * 64, nt = (blockIdx.x & 3) * 64;
    const float* src = (seg < 8) ? W + (size_t)(l * RR + seg) * DD * DD
                                 : Wroot + (size_t)l * DD * DD;
    int t = threadIdx.x;
    #pragma unroll
    for (int i = 0; i < 16; ++i) {
        int row = i * 4 + (t >> 6);
        int col = t & 63;
        tl[row][col] = src[(size_t)(kt + row) * DD + nt + col];
    }
    __syncthreads();
    #pragma unroll
    for (int i = 0; i < 16; ++i) {
        int n = i * 4 + (t >> 6);
        int k = t & 63;
        Wt[((size_t)ls * DD + nt + n) * DD + kt + k] = f2bf(tl[k][n]);
    }
}

// ---------------------------------------------------------------------------
// CSR build step 1: counts[bb][r][dst] += 1 per edge
// ---------------------------------------------------------------------------
__global__ __launch_bounds__(256) void count_k(const int* __restrict__ edges,
                                               const int* __restrict__ types,
                                               int* __restrict__ counts,
                                               int b0, int bc)
{
    int t = blockIdx.x * 256 + threadIdx.x;
    if (t >= bc * EE) return;
    int bb = t / EE;
    int e  = t - bb * EE;
    const int* eb = edges + (size_t)(b0 + bb) * 2 * EE;
    int dst = eb[EE + e];
    int r   = types[(size_t)(b0 + bb) * EE + e];
    atomicAdd(&counts[((size_t)bb * RR + r) * NN + dst], 1);
}

// ---------------------------------------------------------------------------
// CSR build step 2: exclusive scan of counts per batch (16384 entries)
// ---------------------------------------------------------------------------
__global__ __launch_bounds__(256) void scan_k(const int* __restrict__ counts,
                                              int* __restrict__ offsets,
                                              int* __restrict__ cursor)
{
    int bb = blockIdx.x;
    int tid = threadIdx.x;
    size_t base = (size_t)bb * BUCKETS;
    __shared__ int sums[256];

    int tot = 0;
    #pragma unroll 4
    for (int i = 0; i < 64; ++i) tot += counts[base + tid * 64 + i];
    sums[tid] = tot;
    __syncthreads();
    for (int off = 1; off < 256; off <<= 1) {
        int v = (tid >= off) ? sums[tid - off] : 0;
        __syncthreads();
        sums[tid] += v;
        __syncthreads();
    }
    int run = sums[tid] - tot;
    for (int i = 0; i < 64; ++i) {
        size_t idx = base + tid * 64 + i;
        offsets[idx] = run;
        cursor[idx]  = run;
        run += counts[idx];
    }
}

// ---------------------------------------------------------------------------
// deg[bb][n] = sum_r counts[bb][r][n]
// ---------------------------------------------------------------------------
__global__ __launch_bounds__(256) void deg_from_counts(const int* __restrict__ counts,
                                                       float* __restrict__ deg,
                                                       int bc)
{
    int t = blockIdx.x * 256 + threadIdx.x;
    if (t >= bc * NN) return;
    int bb = t / NN;
    int n  = t - bb * NN;
    int d = 0;
    #pragma unroll
    for (int r = 0; r < RR; ++r)
        d += counts[((size_t)bb * RR + r) * NN + n];
    deg[t] = (float)d;
}

// ---------------------------------------------------------------------------
// CSR build step 3: place each edge's src into its bucket slot
// ---------------------------------------------------------------------------
__global__ __launch_bounds__(256) void permute_k(const int* __restrict__ edges,
                                                 const int* __restrict__ types,
                                                 int* __restrict__ cursor,
                                                 int* __restrict__ edgeSrc,
                                                 int b0, int bc)
{
    int t = blockIdx.x * 256 + threadIdx.x;
    if (t >= bc * EE) return;
    int bb = t / EE;
    int e  = t - bb * EE;
    const int* eb = edges + (size_t)(b0 + bb) * 2 * EE;
    int src = eb[e];
    int dst = eb[EE + e];
    int r   = types[(size_t)(b0 + bb) * EE + e];
    int pos = atomicAdd(&cursor[((size_t)bb * RR + r) * NN + dst], 1);
    edgeSrc[(size_t)bb * EE + pos] = src;
}

// ---------------------------------------------------------------------------
// aggregation (atomic-free): one wave per bucket (bb, r, dst), bf16 in/out,
// fp32 accumulate. Lane owns 4 of the 256 columns (ushort4 = 8B).
// ---------------------------------------------------------------------------
__global__ __launch_bounds__(256) void agg_k(const int* __restrict__ offsets,
                                             const int* __restrict__ counts,
                                             const int* __restrict__ edgeSrc,
                                             const u16* __restrict__ xin,
                                             u16* __restrict__ s,
                                             int bc)
{
    int g = blockIdx.x * 4 + (threadIdx.x >> 6);   // bucket id
    int lane = threadIdx.x & 63;
    if (g >= bc * BUCKETS) return;
    int bb  = g >> 14;            // BUCKETS = 2^14
    int start = offsets[g];
    int cnt   = counts[g];
    const u16* xb = xin + (size_t)bb * NN * DD;
    const int* es = edgeSrc + (size_t)bb * EE;
    float a0 = 0.f, a1 = 0.f, a2 = 0.f, a3 = 0.f;
    for (int j = 0; j < cnt; ++j) {
        int src = es[start + j];
        ushort4 v = *((const ushort4*)(xb + (size_t)src * DD) + lane);
        a0 += bf2f(v.x); a1 += bf2f(v.y); a2 += bf2f(v.z); a3 += bf2f(v.w);
    }
    ushort4 o;
    o.x = f2bf(a0); o.y = f2bf(a1); o.z = f2bf(a2); o.w = f2bf(a3);
    *((ushort4*)(s + (size_t)g * DD) + lane) = o;
}

// ---------------------------------------------------------------------------
// MFMA GEMM: out[bb,m,n] = post( (Σ_r s_r@W_r)·invdeg + x@Wroot + b )
// Block = 128x128 tile, 4 waves in 2x2, v_mfma_f32_32x32x16_bf16, BK=32.
// K-loop: 9 segments (8 relations + root) × 8 k-tiles. Staging via
// global_load_lds width=16 (LDS layout strictly lane-linear — no padding).
// Degree normalization applied to acc between segment 7 and the root segment.
// ---------------------------------------------------------------------------
template <int WRITE_BF16>
__global__ __launch_bounds__(256) void rgcn_gemm(const u16* __restrict__ sB,
                                                 const u16* __restrict__ xin,
                                                 const u16* __restrict__ Wt,
                                                 const float* __restrict__ bias,
                                                 const float* __restrict__ deg,
                                                 float* __restrict__ outF,
                                                 u16* __restrict__ outH,
                                                 int relu)
{
    __shared__ __align__(16) u16 Als[128 * 32];   // [m][k], 8 KB
    __shared__ __align__(16) u16 Bls[128 * 32];   // [n][k], 8 KB
    __shared__ float sInv[128];

    int t = threadIdx.x;
    int lane = t & 63, wid = t >> 6;
    int wm = wid & 1, wn = wid >> 1;              // 2x2 wave grid
    int bb = blockIdx.z;
    int m0 = blockIdx.x * 128;
    int n0 = blockIdx.y * 128;

    const u16* xb = xin + (size_t)bb * NN * DD;
    if (t < 128) {
        float dg = deg[(size_t)bb * NN + m0 + t];
        sInv[t] = 1.0f / fmaxf(dg, 1.0f);
    }

    fx16 acc[2][2];
    #pragma unroll
    for (int i = 0; i < 2; ++i)
        #pragma unroll
        for (int j = 0; j < 2; ++j)
            #pragma unroll
            for (int e = 0; e < 16; ++e) acc[i][j][e] = 0.0f;

    int srow = t >> 2;            // staging row 0..63 (per 256-slot call)
    int scol = (t & 3) * 8;       // staging 16B chunk (ushort offset)
    int l31 = lane & 31, lh = lane >> 5;

    for (int seg = 0; seg < 9; ++seg) {
        const u16* Ab;
        const u16* Bb = Wt + (size_t)seg * DD * DD + n0 * DD;
        if (seg < 8) {
            Ab = sB + (((size_t)bb * RR + seg) * NN + m0) * DD;
        } else {
            // normalize aggregation by degree before adding the root term
            #pragma unroll
            for (int mt = 0; mt < 2; ++mt)
                #pragma unroll
                for (int r = 0; r < 16; ++r) {
                    int row = wm * 64 + mt * 32 + (r & 3) + 8 * (r >> 2) + 4 * lh;
                    float iv = sInv[row];
                    acc[mt][0][r] *= iv;
                    acc[mt][1][r] *= iv;
                }
            Ab = xb + (size_t)m0 * DD;
        }
        for (int kt = 0; kt < 8; ++kt) {
            int k0 = kt * 32;
            // stage A (128x32) and B (128x32): 2 async16 calls each per wave
            #pragma unroll
            for (int i = 0; i < 2; ++i) {
                async16(Ab + (size_t)(i * 64 + srow) * DD + k0 + scol,
                        Als + i * 2048 + wid * 512);
                async16(Bb + (size_t)(i * 64 + srow) * DD + k0 + scol,
                        Bls + i * 2048 + wid * 512);
            }
            __syncthreads();   // drains vmcnt (global_load_lds) for all waves

            bfx8 af[2][2], bfr[2][2];
            #pragma unroll
            for (int mt = 0; mt < 2; ++mt)
                #pragma unroll
                for (int ks = 0; ks < 2; ++ks)
                    af[mt][ks] = *(const bfx8*)&Als[(wm * 64 + mt * 32 + l31) * 32 + ks * 16 + lh * 8];
            #pragma unroll
            for (int nt = 0; nt < 2; ++nt)
                #pragma unroll
                for (int ks = 0; ks < 2; ++ks)
                    bfr[nt][ks] = *(const bfx8*)&Bls[(wn * 64 + nt * 32 + l31) * 32 + ks * 16 + lh * 8];
            #pragma unroll
            for (int ks = 0; ks < 2; ++ks)
                #pragma unroll
                for (int mt = 0; mt < 2; ++mt)
                    #pragma unroll
                    for (int nt = 0; nt < 2; ++nt)
                        acc[mt][nt] = __builtin_amdgcn_mfma_f32_32x32x16_bf16(
                            af[mt][ks], bfr[nt][ks], acc[mt][nt], 0, 0, 0);
            __syncthreads();   // readers done before next iter's staging
        }
    }

    // epilogue: bias (+relu), store bf16 (mid-layer) or fp32 (final)
    #pragma unroll
    for (int mt = 0; mt < 2; ++mt)
        #pragma unroll
        for (int nt = 0; nt < 2; ++nt) {
            int col = n0 + wn * 64 + nt * 32 + l31;
            float bv = bias[col];
            #pragma unroll
            for (int r = 0; r < 16; ++r) {
                int row = m0 + wm * 64 + mt * 32 + (r & 3) + 8 * (r >> 2) + 4 * lh;
                float v = acc[mt][nt][r] + bv;
                if (relu) v = fmaxf(v, 0.0f);
                if (WRITE_BF16)
                    outH[((size_t)bb * NN + row) * DD + col] = f2bf(v);
                else
                    outF[((size_t)bb * NN + row) * DD + col] = v;
            }
        }
}

// ---------------------------------------------------------------------------
extern "C" void kernel_launch(void* const* d_in, const int* in_sizes, int n_in,
                              void* d_out, int out_size, void* d_ws, size_t ws_size,
                              hipStream_t stream)
{
    const int*   nodes = (const int*)d_in[0];
    const int*   edges = (const int*)d_in[1];
    const int*   types = (const int*)d_in[2];
    const float* emb   = (const float*)d_in[3];
    const float* W     = (const float*)d_in[4];
    const float* Wroot = (const float*)d_in[5];
    const float* bias  = (const float*)d_in[6];
    float* out = (float*)d_out;

    // fixed: Wt (L*9*D*D bf16); per-batch: sBuf + x0 + x1 (bf16), deg (f32),
    // counts/offsets/cursor/edgeSrc (int)
    const size_t wtBytes = (size_t)LL * 9 * DD * DD * sizeof(u16);
    const size_t perBatchBytes =
        ((size_t)RR * NN * DD + 2 * (size_t)NN * DD) * sizeof(u16) +
        (size_t)NN * sizeof(float) +
        (3 * (size_t)BUCKETS + EE) * sizeof(int);
    int BC = (int)((ws_size - wtBytes) / perBatchBytes);
    if (BC > BB) BC = BB;
    if (BC < 1) BC = 1;

    u16* Wt   = (u16*)d_ws;
    u16* sBuf = Wt + (size_t)LL * 9 * DD * DD;
    u16* x0   = sBuf + (size_t)BC * RR * NN * DD;
    u16* x1   = x0 + (size_t)BC * NN * DD;
    float* deg = (float*)(x1 + (size_t)BC * NN * DD);
    int* counts  = (int*)(deg + (size_t)BC * NN);
    int* offsets = counts + (size_t)BC * BUCKETS;
    int* cursor  = offsets + (size_t)BC * BUCKETS;
    int* edgeSrc = cursor + (size_t)BC * BUCKETS;

    wt_k<<<dim3(16, LL * 9), 256, 0, stream>>>(W, Wroot, Wt);

    for (int b0 = 0; b0 < BB; b0 += BC) {
        int bc = BB - b0 < BC ? BB - b0 : BC;

        // ---- CSR build (once per chunk; dst/type are layer-invariant) ----
        hipMemsetAsync(counts, 0, (size_t)bc * BUCKETS * sizeof(int), stream);
        gather_k<<<bc * 512, 256, 0, stream>>>(nodes, emb, x0, b0, bc);
        count_k<<<bc * (EE / 256), 256, 0, stream>>>(edges, types, counts, b0, bc);
        scan_k<<<bc, 256, 0, stream>>>(counts, offsets, cursor);
        deg_from_counts<<<bc * (NN / 256), 256, 0, stream>>>(counts, deg, bc);
        permute_k<<<bc * (EE / 256), 256, 0, stream>>>(edges, types, cursor, edgeSrc, b0, bc);

        for (int l = 0; l < LL; ++l) {
            const u16* xin = (l == 0) ? x0 : x1;
            agg_k<<<bc * (BUCKETS / 4), 256, 0, stream>>>(offsets, counts, edgeSrc, xin, sBuf, bc);
            const u16* Wtl = Wt + (size_t)l * 9 * DD * DD;
            dim3 grid(NN / 128, DD / 128, bc);
            if (l == 0)
                rgcn_gemm<1><<<grid, 256, 0, stream>>>(sBuf, xin, Wtl,
                    bias + (size_t)l * DD, deg, nullptr, x1, 1);
            else
                rgcn_gemm<0><<<grid, 256, 0, stream>>>(sBuf, xin, Wtl,
                    bias + (size_t)l * DD, deg, out + (size_t)b0 * NN * DD, nullptr, 0);
        }
    }
}

// Round 4
// 364.878 us; speedup vs baseline: 12.9948x; 1.2631x over previous
//
#include <hip/hip_runtime.h>

// Problem constants (match reference setup_inputs)
#define BB 16
#define NN 2048
#define EE 32768
#define DD 256
#define RR 8
#define LL 2
#define BUCKETS (RR * NN)   // 16384 buckets per batch
#define TM 64               // GEMM m-tile

typedef unsigned short u16;
typedef __attribute__((__ext_vector_type__(8))) __bf16 bfx8;   // MFMA A/B frag
typedef __attribute__((__ext_vector_type__(16))) float fx16;   // MFMA acc

__device__ __forceinline__ float blo(unsigned u){ union{unsigned x;float f;}c; c.x=u<<16; return c.f; }
__device__ __forceinline__ float bhi(unsigned u){ union{unsigned x;float f;}c; c.x=u&0xffff0000u; return c.f; }
__device__ __forceinline__ u16 f2bf(float f){ union{float f;unsigned u;}x; x.f=f;
    return (u16)((x.u + 0x7FFFu + ((x.u>>16)&1u))>>16); }           // RNE
__device__ __forceinline__ unsigned pk2(float a, float b){
    return (unsigned)f2bf(a) | ((unsigned)f2bf(b)<<16); }

// ---------------------------------------------------------------------------
// gather: x0[bb, n, :] = bf16(emb[nodes[b0+bb, n], :])
// ---------------------------------------------------------------------------
__global__ __launch_bounds__(256) void gather_k(const int* __restrict__ nodes,
                                                const float* __restrict__ emb,
                                                u16* __restrict__ x0,
                                                int b0, int bc)
{
    int t = blockIdx.x * 256 + threadIdx.x;
    int lane = t & 63;
    int row = t >> 6;
    if (row >= bc * NN) return;
    int bb = row / NN;
    int n  = row - bb * NN;
    int v  = nodes[(size_t)(b0 + bb) * NN + n];
    float4 val = *((const float4*)(emb + (size_t)v * DD) + lane);
    ushort4 o;
    o.x = f2bf(val.x); o.y = f2bf(val.y); o.z = f2bf(val.z); o.w = f2bf(val.w);
    *((ushort4*)(x0 + (size_t)row * DD) + lane) = o;
}

// ---------------------------------------------------------------------------
// weight prep into MFMA-B fragment order:
// Wf[ls][kt(8)][nt8(8)][ks2(2)][fl(64)][e(8)] (bf16), where for frag lane fl:
//   n = nt8*32 + (fl&31), k = kt*32 + ks2*16 + (fl>>5)*8 + e, value = Wsrc[k][n]
// grid = (8 kt, LL*9)
// ---------------------------------------------------------------------------
__global__ __launch_bounds__(256) void wt_k(const float* __restrict__ W,
                                            const float* __restrict__ Wroot,
                                            u16* __restrict__ Wf)
{
    __shared__ float tl[32][257];   // [k][n], padded
    int ls = blockIdx.y;            // l*9 + seg
    int l = ls / 9, seg = ls - l * 9;
    int kt = blockIdx.x;
    const float* src = (seg < 8) ? W + (size_t)(l * RR + seg) * DD * DD
                                 : Wroot + (size_t)l * DD * DD;
    int t = threadIdx.x;
    for (int k8 = 0; k8 < 32; ++k8)
        tl[k8][t] = src[(size_t)(kt * 32 + k8) * DD + t];
    __syncthreads();
    // 1024 octets per (ls, kt); 256 threads x 4
    #pragma unroll
    for (int i = 0; i < 4; ++i) {
        int o = i * 256 + t;                 // o = nt8*128 + ks2*64 + fl
        int fl = o & 63, ks2 = (o >> 6) & 1, nt8 = o >> 7;
        int n = nt8 * 32 + (fl & 31);
        int kb = ks2 * 16 + (fl >> 5) * 8;
        unsigned d0 = pk2(tl[kb + 0][n], tl[kb + 1][n]);
        unsigned d1 = pk2(tl[kb + 2][n], tl[kb + 3][n]);
        unsigned d2 = pk2(tl[kb + 4][n], tl[kb + 5][n]);
        unsigned d3 = pk2(tl[kb + 6][n], tl[kb + 7][n]);
        *(uint4*)(Wf + (((size_t)ls * 8 + kt) * 1024 + o) * 8) =
            make_uint4(d0, d1, d2, d3);
    }
}

// ---------------------------------------------------------------------------
// CSR build step 1: counts[bb][r][dst] += 1 per edge
// ---------------------------------------------------------------------------
__global__ __launch_bounds__(256) void count_k(const int* __restrict__ edges,
                                               const int* __restrict__ types,
                                               int* __restrict__ counts,
                                               int b0, int bc)
{
    int t = blockIdx.x * 256 + threadIdx.x;
    if (t >= bc * EE) return;
    int bb = t / EE;
    int e  = t - bb * EE;
    const int* eb = edges + (size_t)(b0 + bb) * 2 * EE;
    int dst = eb[EE + e];
    int r   = types[(size_t)(b0 + bb) * EE + e];
    atomicAdd(&counts[((size_t)bb * RR + r) * NN + dst], 1);
}

// ---------------------------------------------------------------------------
// CSR scan, 3 stages (parallel; replaces the 16-block serial scan)
// ---------------------------------------------------------------------------
__global__ __launch_bounds__(256) void sect_k(const int* __restrict__ counts,
                                              int* __restrict__ secsum)
{
    __shared__ int red[256];
    int sec = blockIdx.x;                    // bb*8 + r
    int t = threadIdx.x;
    size_t base = (size_t)sec * NN;
    int s = 0;
    #pragma unroll
    for (int i = 0; i < 8; ++i) s += counts[base + t * 8 + i];
    red[t] = s;
    __syncthreads();
    for (int off = 128; off > 0; off >>= 1) {
        if (t < off) red[t] += red[t + off];
        __syncthreads();
    }
    if (t == 0) secsum[sec] = red[0];
}

__global__ __launch_bounds__(128) void base_k(const int* __restrict__ secsum,
                                              int* __restrict__ secbase, int nsec)
{
    int t = threadIdx.x;
    if (t >= nsec) return;
    int bb = t >> 3;
    int s = 0;
    for (int i = bb * 8; i < t; ++i) s += secsum[i];
    secbase[t] = s;                          // exclusive within batch bb
}

__global__ __launch_bounds__(256) void offs_k(const int* __restrict__ counts,
                                              const int* __restrict__ secbase,
                                              int* __restrict__ offsets,
                                              int* __restrict__ cursor)
{
    __shared__ int sums[256];
    int sec = blockIdx.x;
    int t = threadIdx.x;
    size_t base = (size_t)sec * NN;
    int v[8], s = 0;
    #pragma unroll
    for (int i = 0; i < 8; ++i) { v[i] = counts[base + t * 8 + i]; s += v[i]; }
    sums[t] = s;
    __syncthreads();
    for (int off = 1; off < 256; off <<= 1) {
        int x = (t >= off) ? sums[t - off] : 0;
        __syncthreads();
        sums[t] += x;
        __syncthreads();
    }
    int run = secbase[sec] + sums[t] - s;
    #pragma unroll
    for (int i = 0; i < 8; ++i) {
        offsets[base + t * 8 + i] = run;
        cursor[base + t * 8 + i]  = run;
        run += v[i];
    }
}

// ---------------------------------------------------------------------------
// deg[bb][n] = sum_r counts[bb][r][n]
// ---------------------------------------------------------------------------
__global__ __launch_bounds__(256) void deg_from_counts(const int* __restrict__ counts,
                                                       float* __restrict__ deg,
                                                       int bc)
{
    int t = blockIdx.x * 256 + threadIdx.x;
    if (t >= bc * NN) return;
    int bb = t / NN;
    int n  = t - bb * NN;
    int d = 0;
    #pragma unroll
    for (int r = 0; r < RR; ++r)
        d += counts[((size_t)bb * RR + r) * NN + n];
    deg[t] = (float)d;
}

// ---------------------------------------------------------------------------
// CSR build step 3: place each edge's src into its bucket slot
// ---------------------------------------------------------------------------
__global__ __launch_bounds__(256) void permute_k(const int* __restrict__ edges,
                                                 const int* __restrict__ types,
                                                 int* __restrict__ cursor,
                                                 int* __restrict__ edgeSrc,
                                                 int b0, int bc)
{
    int t = blockIdx.x * 256 + threadIdx.x;
    if (t >= bc * EE) return;
    int bb = t / EE;
    int e  = t - bb * EE;
    const int* eb = edges + (size_t)(b0 + bb) * 2 * EE;
    int src = eb[e];
    int dst = eb[EE + e];
    int r   = types[(size_t)(b0 + bb) * EE + e];
    int pos = atomicAdd(&cursor[((size_t)bb * RR + r) * NN + dst], 1);
    edgeSrc[(size_t)bb * EE + pos] = src;
}

// ---------------------------------------------------------------------------
// FUSED agg + GEMM: out[bb,m,:] = post( (Σ_r agg_r(x) @ W_r)·invdeg + x@Wroot + b )
// Block: 64 m-rows × 256 n (full D), 512 threads (8 waves), 2 blocks/CU.
// Per segment: 16-lane groups aggregate each row's CSR bucket in fp32 regs and
// write bf16 A directly to LDS in MFMA-frag layout (ks-rotated: conflict-free
// both sides). K-loop: A frags from LDS, B frags straight from L2-resident
// frag-ordered Wf. Only 2 barriers per segment.
// A_lds[mt(2)][ks(16)][slot(64)]x16B, slot = (fl + ks) & 63.
// ---------------------------------------------------------------------------
template <int WRITE_BF16>
__global__ __launch_bounds__(512, 4) void rgcn_fused(
    const int* __restrict__ offsets, const int* __restrict__ counts,
    const int* __restrict__ edgeSrc, const u16* __restrict__ xin,
    const u16* __restrict__ Wf,      // this layer's frag weights: [9][8][1024][8]
    const float* __restrict__ bias, const float* __restrict__ deg,
    float* __restrict__ outF, u16* __restrict__ outH, int relu)
{
    __shared__ __align__(16) u16 Af[2 * 16 * 64 * 8];   // 32 KB
    __shared__ float sInv[TM];

    int t = threadIdx.x;
    int fl = t & 63;
    int wid = t >> 6;            // wave id = n-tile (32 cols each)
    int bb = blockIdx.y;
    int m0 = blockIdx.x * TM;

    if (t < TM) sInv[t] = 1.0f / fmaxf(deg[(size_t)bb * NN + m0 + t], 1.0f);

    const u16* xb = xin + (size_t)bb * NN * DD;
    const int* es = edgeSrc + (size_t)bb * EE;

    // A-build coords: 32 groups of 16 lanes; group handles 2 rows
    int gid = t >> 4;
    int j16 = t & 15;
    int ks0 = j16 >> 1;          // frag ks (part0); part1 = ks0+8
    int lh2 = j16 & 1;

    fx16 acc[2];
    #pragma unroll
    for (int mt = 0; mt < 2; ++mt)
        #pragma unroll
        for (int e = 0; e < 16; ++e) acc[mt][e] = 0.0f;

    int lh = fl >> 5;            // for acc row mapping / frag k-half

    for (int seg = 0; seg < 9; ++seg) {
        __syncthreads();         // prior segment's frag reads complete
        // ---- build A-tile for this segment ----
        #pragma unroll
        for (int rr = 0; rr < 2; ++rr) {
            int row = gid * 2 + rr;
            int mt = row >> 5, m31 = row & 31;
            int flw = m31 + 32 * lh2;
            unsigned w0, w1, w2, w3, w4, w5, w6, w7;
            if (seg < 8) {
                float a[16];
                #pragma unroll
                for (int e = 0; e < 16; ++e) a[e] = 0.0f;
                int g = ((bb * RR + seg) * NN) + m0 + row;
                int start = offsets[g];
                int cnt   = counts[g];
                for (int jj = 0; jj < cnt; ++jj) {
                    int src = es[start + jj];
                    const u16* xr = xb + (size_t)src * DD;
                    uint4 p0 = *(const uint4*)(xr + j16 * 8);
                    uint4 p1 = *(const uint4*)(xr + 128 + j16 * 8);
                    a[0] += blo(p0.x); a[1] += bhi(p0.x);
                    a[2] += blo(p0.y); a[3] += bhi(p0.y);
                    a[4] += blo(p0.z); a[5] += bhi(p0.z);
                    a[6] += blo(p0.w); a[7] += bhi(p0.w);
                    a[8]  += blo(p1.x); a[9]  += bhi(p1.x);
                    a[10] += blo(p1.y); a[11] += bhi(p1.y);
                    a[12] += blo(p1.z); a[13] += bhi(p1.z);
                    a[14] += blo(p1.w); a[15] += bhi(p1.w);
                }
                w0 = pk2(a[0], a[1]);   w1 = pk2(a[2], a[3]);
                w2 = pk2(a[4], a[5]);   w3 = pk2(a[6], a[7]);
                w4 = pk2(a[8], a[9]);   w5 = pk2(a[10], a[11]);
                w6 = pk2(a[12], a[13]); w7 = pk2(a[14], a[15]);
            } else {
                // root segment: A = x rows (already bf16 — direct copy)
                const u16* xr = xb + (size_t)(m0 + row) * DD;
                uint4 p0 = *(const uint4*)(xr + j16 * 8);
                uint4 p1 = *(const uint4*)(xr + 128 + j16 * 8);
                w0 = p0.x; w1 = p0.y; w2 = p0.z; w3 = p0.w;
                w4 = p1.x; w5 = p1.y; w6 = p1.z; w7 = p1.w;
            }
            int c0 = ((mt * 16 + ks0) * 64 + ((flw + ks0) & 63)) * 8;
            int c1 = ((mt * 16 + ks0 + 8) * 64 + ((flw + ks0 + 8) & 63)) * 8;
            *(uint4*)&Af[c0] = make_uint4(w0, w1, w2, w3);
            *(uint4*)&Af[c1] = make_uint4(w4, w5, w6, w7);
        }
        __syncthreads();         // A visible to all waves

        if (seg == 8) {
            // normalize aggregation by degree before the root term
            #pragma unroll
            for (int mt = 0; mt < 2; ++mt)
                #pragma unroll
                for (int r = 0; r < 16; ++r) {
                    int rl = mt * 32 + (r & 3) + 8 * (r >> 2) + 4 * lh;
                    acc[mt][r] *= sInv[rl];
                }
        }

        // ---- K loop: 8 k-tiles of 32, no barriers ----
        const u16* Wseg = Wf + (size_t)seg * 65536;
        #pragma unroll 2
        for (int kt = 0; kt < 8; ++kt) {
            bfx8 bfr[2], af[2][2];
            #pragma unroll
            for (int ks2 = 0; ks2 < 2; ++ks2) {
                int ksA = kt * 2 + ks2;
                bfr[ks2] = *(const bfx8*)(Wseg + (size_t)kt * 8192 + wid * 1024
                                          + ks2 * 512 + fl * 8);
                af[0][ks2] = *(const bfx8*)&Af[((0  + ksA) * 64 + ((fl + ksA) & 63)) * 8];
                af[1][ks2] = *(const bfx8*)&Af[((16 + ksA) * 64 + ((fl + ksA) & 63)) * 8];
            }
            #pragma unroll
            for (int ks2 = 0; ks2 < 2; ++ks2) {
                acc[0] = __builtin_amdgcn_mfma_f32_32x32x16_bf16(af[0][ks2], bfr[ks2], acc[0], 0, 0, 0);
                acc[1] = __builtin_amdgcn_mfma_f32_32x32x16_bf16(af[1][ks2], bfr[ks2], acc[1], 0, 0, 0);
            }
        }
    }

    // ---- epilogue ----
    int col = wid * 32 + (fl & 31);
    float bv = bias[col];
    #pragma unroll
    for (int mt = 0; mt < 2; ++mt)
        #pragma unroll
        for (int r = 0; r < 16; ++r) {
            int row = m0 + mt * 32 + (r & 3) + 8 * (r >> 2) + 4 * lh;
            float v = acc[mt][r] + bv;
            if (relu) v = fmaxf(v, 0.0f);
            if (WRITE_BF16)
                outH[((size_t)bb * NN + row) * DD + col] = f2bf(v);
            else
                outF[((size_t)bb * NN + row) * DD + col] = v;
        }
}

// ---------------------------------------------------------------------------
extern "C" void kernel_launch(void* const* d_in, const int* in_sizes, int n_in,
                              void* d_out, int out_size, void* d_ws, size_t ws_size,
                              hipStream_t stream)
{
    const int*   nodes = (const int*)d_in[0];
    const int*   edges = (const int*)d_in[1];
    const int*   types = (const int*)d_in[2];
    const float* emb   = (const float*)d_in[3];
    const float* W     = (const float*)d_in[4];
    const float* Wroot = (const float*)d_in[5];
    const float* bias  = (const float*)d_in[6];
    float* out = (float*)d_out;

    // fixed: Wf (LL*9*8*1024*8 bf16) + secsum/secbase (128 ints each)
    // per-batch: x0,x1 bf16 + deg f32 + counts/offsets/cursor + edgeSrc ints
    const size_t wfElems = (size_t)LL * 9 * 8 * 1024 * 8;
    const size_t fixedBytes = wfElems * sizeof(u16) + 256 * sizeof(int);
    const size_t perBatchBytes =
        2 * (size_t)NN * DD * sizeof(u16) + (size_t)NN * sizeof(float) +
        (3 * (size_t)BUCKETS + EE) * sizeof(int);
    int BC = (int)((ws_size - fixedBytes) / perBatchBytes);
    if (BC > BB) BC = BB;
    if (BC < 1) BC = 1;

    u16* Wf      = (u16*)d_ws;
    int* secsum  = (int*)(Wf + wfElems);
    int* secbase = secsum + 128;
    u16* x0      = (u16*)(secbase + 128);
    u16* x1      = x0 + (size_t)BC * NN * DD;
    float* deg   = (float*)(x1 + (size_t)BC * NN * DD);
    int* counts  = (int*)(deg + (size_t)BC * NN);
    int* offsets = counts + (size_t)BC * BUCKETS;
    int* cursor  = offsets + (size_t)BC * BUCKETS;
    int* edgeSrc = cursor + (size_t)BC * BUCKETS;

    wt_k<<<dim3(8, LL * 9), 256, 0, stream>>>(W, Wroot, Wf);

    for (int b0 = 0; b0 < BB; b0 += BC) {
        int bc = BB - b0 < BC ? BB - b0 : BC;

        // ---- CSR build (dst/type are layer-invariant) ----
        hipMemsetAsync(counts, 0, (size_t)bc * BUCKETS * sizeof(int), stream);
        gather_k<<<bc * 512, 256, 0, stream>>>(nodes, emb, x0, b0, bc);
        count_k<<<bc * (EE / 256), 256, 0, stream>>>(edges, types, counts, b0, bc);
        sect_k<<<bc * 8, 256, 0, stream>>>(counts, secsum);
        base_k<<<1, 128, 0, stream>>>(secsum, secbase, bc * 8);
        offs_k<<<bc * 8, 256, 0, stream>>>(counts, secbase, offsets, cursor);
        deg_from_counts<<<bc * (NN / 256), 256, 0, stream>>>(counts, deg, bc);
        permute_k<<<bc * (EE / 256), 256, 0, stream>>>(edges, types, cursor, edgeSrc, b0, bc);

        for (int l = 0; l < LL; ++l) {
            const u16* xin = (l == 0) ? x0 : x1;
            const u16* Wfl = Wf + (size_t)l * 9 * 65536;
            dim3 grid(NN / TM, bc);
            if (l == 0)
                rgcn_fused<1><<<grid, 512, 0, stream>>>(offsets, counts, edgeSrc,
                    xin, Wfl, bias + (size_t)l * DD, deg, nullptr, x1, 1);
            else
                rgcn_fused<0><<<grid, 512, 0, stream>>>(offsets, counts, edgeSrc,
                    xin, Wfl, bias + (size_t)l * DD, deg,
                    out + (size_t)b0 * NN * DD, nullptr, 0);
        }
    }
}

// Round 5
// 301.047 us; speedup vs baseline: 15.7501x; 1.2120x over previous
//
#include <hip/hip_runtime.h>

// Problem constants (match reference setup_inputs)
#define BB 16
#define NN 2048
#define EE 32768
#define DD 256
#define RR 8
#define LL 2
#define BUCKETS (RR * NN)   // 16384 buckets per batch
#define TM 64               // GEMM m-tile

typedef unsigned short u16;
typedef __attribute__((__ext_vector_type__(8))) __bf16 bfx8;   // MFMA A/B frag
typedef __attribute__((__ext_vector_type__(16))) float fx16;   // MFMA acc

__device__ __forceinline__ float blo(unsigned u){ union{unsigned x;float f;}c; c.x=u<<16; return c.f; }
__device__ __forceinline__ float bhi(unsigned u){ union{unsigned x;float f;}c; c.x=u&0xffff0000u; return c.f; }
__device__ __forceinline__ u16 f2bf(float f){ union{float f;unsigned u;}x; x.f=f;
    return (u16)((x.u + 0x7FFFu + ((x.u>>16)&1u))>>16); }           // RNE
__device__ __forceinline__ unsigned pk2(float a, float b){
    return (unsigned)f2bf(a) | ((unsigned)f2bf(b)<<16); }
__device__ __forceinline__ void acc8(float* a, uint4 p0, uint4 p1) {
    a[0]+=blo(p0.x); a[1]+=bhi(p0.x); a[2]+=blo(p0.y); a[3]+=bhi(p0.y);
    a[4]+=blo(p0.z); a[5]+=bhi(p0.z); a[6]+=blo(p0.w); a[7]+=bhi(p0.w);
    a[8]+=blo(p1.x); a[9]+=bhi(p1.x); a[10]+=blo(p1.y); a[11]+=bhi(p1.y);
    a[12]+=blo(p1.z); a[13]+=bhi(p1.z); a[14]+=blo(p1.w); a[15]+=bhi(p1.w);
}

// ---------------------------------------------------------------------------
// prep0: (a) weight prep into MFMA-B fragment order (144 blocks)
//        Wf[ls][kt(8)][nt8(8)][ks2(2)][fl(64)][e(8)] bf16,
//        n = nt8*32+(fl&31), k = kt*32+ks2*16+(fl>>5)*8+e, val = Wsrc[k][n]
//        (b) zero counts (remaining blocks)
// ---------------------------------------------------------------------------
__global__ __launch_bounds__(256) void prep0(const float* __restrict__ W,
                                             const float* __restrict__ Wroot,
                                             u16* __restrict__ Wf,
                                             int* __restrict__ counts, int bc)
{
    int t = threadIdx.x;
    if (blockIdx.x < 8 * LL * 9) {
        __shared__ float tl[32][257];   // [k][n], padded
        int kt = blockIdx.x & 7, ls = blockIdx.x >> 3;
        int l = ls / 9, seg = ls - l * 9;
        const float* src = (seg < 8) ? W + (size_t)(l * RR + seg) * DD * DD
                                     : Wroot + (size_t)l * DD * DD;
        for (int k8 = 0; k8 < 32; ++k8)
            tl[k8][t] = src[(size_t)(kt * 32 + k8) * DD + t];
        __syncthreads();
        #pragma unroll
        for (int i = 0; i < 4; ++i) {
            int o = i * 256 + t;                 // o = nt8*128 + ks2*64 + fl
            int fl = o & 63, ks2 = (o >> 6) & 1, nt8 = o >> 7;
            int n = nt8 * 32 + (fl & 31);
            int kb = ks2 * 16 + (fl >> 5) * 8;
            unsigned d0 = pk2(tl[kb + 0][n], tl[kb + 1][n]);
            unsigned d1 = pk2(tl[kb + 2][n], tl[kb + 3][n]);
            unsigned d2 = pk2(tl[kb + 4][n], tl[kb + 5][n]);
            unsigned d3 = pk2(tl[kb + 6][n], tl[kb + 7][n]);
            *(uint4*)(Wf + (((size_t)ls * 8 + kt) * 1024 + o) * 8) =
                make_uint4(d0, d1, d2, d3);
        }
    } else {
        int idx = (blockIdx.x - 8 * LL * 9) * 256 + t;   // int4 granules
        int tot = bc * BUCKETS / 4;
        if (idx < tot) ((int4*)counts)[idx] = make_int4(0, 0, 0, 0);
    }
}

// ---------------------------------------------------------------------------
// prep1: (a) gather x0 = bf16(emb[nodes]) (bc*512 blocks)
//        (b) counts[bb][r][dst] += 1 per edge (bc*128 blocks)
// ---------------------------------------------------------------------------
__global__ __launch_bounds__(256) void prep1(const int* __restrict__ nodes,
                                             const float* __restrict__ emb,
                                             u16* __restrict__ x0,
                                             const int* __restrict__ edges,
                                             const int* __restrict__ types,
                                             int* __restrict__ counts,
                                             int b0, int bc)
{
    int ng = bc * 512;
    if ((int)blockIdx.x < ng) {
        int t = blockIdx.x * 256 + threadIdx.x;
        int lane = t & 63;
        int row = t >> 6;
        int bb = row / NN;
        int n  = row - bb * NN;
        int v  = nodes[(size_t)(b0 + bb) * NN + n];
        float4 val = *((const float4*)(emb + (size_t)v * DD) + lane);
        ushort4 o;
        o.x = f2bf(val.x); o.y = f2bf(val.y); o.z = f2bf(val.z); o.w = f2bf(val.w);
        *((ushort4*)(x0 + (size_t)row * DD) + lane) = o;
    } else {
        int t = (blockIdx.x - ng) * 256 + threadIdx.x;
        int bb = t / EE;
        int e  = t - bb * EE;
        const int* eb = edges + (size_t)(b0 + bb) * 2 * EE;
        int dst = eb[EE + e];
        int r   = types[(size_t)(b0 + bb) * EE + e];
        atomicAdd(&counts[((size_t)bb * RR + r) * NN + dst], 1);
    }
}

// ---------------------------------------------------------------------------
// scan2: per-batch exclusive scan of counts (16384 buckets) -> offsets+cursor,
// plus invdeg[bb][n] = 1/max(sum_r counts, 1). One block per batch.
// ---------------------------------------------------------------------------
__global__ __launch_bounds__(256) void scan2_k(const int* __restrict__ counts,
                                               int* __restrict__ offsets,
                                               int* __restrict__ cursor,
                                               float* __restrict__ invdeg)
{
    int bb = blockIdx.x;
    int tid = threadIdx.x;
    size_t base = (size_t)bb * BUCKETS;
    __shared__ int sums[256];

    int tot = 0;
    #pragma unroll 4
    for (int i = 0; i < 64; ++i) tot += counts[base + tid * 64 + i];
    sums[tid] = tot;
    __syncthreads();
    for (int off = 1; off < 256; off <<= 1) {
        int v = (tid >= off) ? sums[tid - off] : 0;
        __syncthreads();
        sums[tid] += v;
        __syncthreads();
    }
    int run = sums[tid] - tot;
    for (int i = 0; i < 64; ++i) {
        size_t idx = base + tid * 64 + i;
        offsets[idx] = run;
        cursor[idx]  = run;
        run += counts[idx];
    }
    // invdeg: thread handles 8 consecutive n
    #pragma unroll
    for (int i = 0; i < 8; ++i) {
        int n = tid * 8 + i;
        int d = 0;
        #pragma unroll
        for (int r = 0; r < RR; ++r)
            d += counts[base + (size_t)r * NN + n];
        invdeg[(size_t)bb * NN + n] = 1.0f / fmaxf((float)d, 1.0f);
    }
}

// ---------------------------------------------------------------------------
// place each edge's src into its bucket slot
// ---------------------------------------------------------------------------
__global__ __launch_bounds__(256) void permute_k(const int* __restrict__ edges,
                                                 const int* __restrict__ types,
                                                 int* __restrict__ cursor,
                                                 int* __restrict__ edgeSrc,
                                                 int b0, int bc)
{
    int t = blockIdx.x * 256 + threadIdx.x;
    int bb = t / EE;
    int e  = t - bb * EE;
    const int* eb = edges + (size_t)(b0 + bb) * 2 * EE;
    int src = eb[e];
    int dst = eb[EE + e];
    int r   = types[(size_t)(b0 + bb) * EE + e];
    int pos = atomicAdd(&cursor[((size_t)bb * RR + r) * NN + dst], 1);
    edgeSrc[(size_t)bb * EE + pos] = src;
}

// ---------------------------------------------------------------------------
// build one segment's A-tile (64 rows x 256 k, bf16, MFMA-frag layout with
// ks-rotation) into LDS buffer A. 16-lane groups, 2 rows/group, cnt unroll x2.
// ---------------------------------------------------------------------------
__device__ __forceinline__ void build_seg(int seg, u16* A,
                                          const int* sStart, const int* sCnt,
                                          const int* es, const u16* xb, int m0,
                                          int gid, int j16, int ks0, int lh2)
{
    #pragma unroll
    for (int rr = 0; rr < 2; ++rr) {
        int row = gid * 2 + rr;
        int mt = row >> 5, m31 = row & 31;
        int flw = m31 + 32 * lh2;
        unsigned w0, w1, w2, w3, w4, w5, w6, w7;
        if (seg < 8) {
            float a[16];
            #pragma unroll
            for (int e = 0; e < 16; ++e) a[e] = 0.0f;
            int start = sStart[seg * TM + row];
            int cnt   = sCnt[seg * TM + row];
            const int* ep = es + start;
            int jj = 0;
            for (; jj + 2 <= cnt; jj += 2) {
                int s0 = ep[jj], s1 = ep[jj + 1];
                const u16* xr0 = xb + (size_t)s0 * DD;
                const u16* xr1 = xb + (size_t)s1 * DD;
                uint4 p0 = *(const uint4*)(xr0 + j16 * 8);
                uint4 p1 = *(const uint4*)(xr0 + 128 + j16 * 8);
                uint4 q0 = *(const uint4*)(xr1 + j16 * 8);
                uint4 q1 = *(const uint4*)(xr1 + 128 + j16 * 8);
                acc8(a, p0, p1);
                acc8(a, q0, q1);
            }
            if (jj < cnt) {
                const u16* xr0 = xb + (size_t)ep[jj] * DD;
                uint4 p0 = *(const uint4*)(xr0 + j16 * 8);
                uint4 p1 = *(const uint4*)(xr0 + 128 + j16 * 8);
                acc8(a, p0, p1);
            }
            w0 = pk2(a[0], a[1]);   w1 = pk2(a[2], a[3]);
            w2 = pk2(a[4], a[5]);   w3 = pk2(a[6], a[7]);
            w4 = pk2(a[8], a[9]);   w5 = pk2(a[10], a[11]);
            w6 = pk2(a[12], a[13]); w7 = pk2(a[14], a[15]);
        } else {
            // root segment: A = x rows (already bf16 — direct copy)
            const u16* xr = xb + (size_t)(m0 + row) * DD;
            uint4 p0 = *(const uint4*)(xr + j16 * 8);
            uint4 p1 = *(const uint4*)(xr + 128 + j16 * 8);
            w0 = p0.x; w1 = p0.y; w2 = p0.z; w3 = p0.w;
            w4 = p1.x; w5 = p1.y; w6 = p1.z; w7 = p1.w;
        }
        int c0 = ((mt * 16 + ks0) * 64 + ((flw + ks0) & 63)) * 8;
        int c1 = ((mt * 16 + ks0 + 8) * 64 + ((flw + ks0 + 8) & 63)) * 8;
        *(uint4*)&A[c0] = make_uint4(w0, w1, w2, w3);
        *(uint4*)&A[c1] = make_uint4(w4, w5, w6, w7);
    }
}

// ---------------------------------------------------------------------------
// FUSED agg + GEMM, double-buffered A, 1 barrier/segment.
// Block: 64 m-rows x 256 n, 512 threads (8 waves), 2 blocks/CU (70 KB LDS).
// XCD swizzle (bc==16): batch's 32 blocks share bid%8 -> its 1 MB x stays in
// one XCD's L2 (2 batches = 2 MB < 4 MB).
// ---------------------------------------------------------------------------
template <int WRITE_BF16>
__global__ __launch_bounds__(512, 4) void rgcn_fused(
    const int* __restrict__ offsets, const int* __restrict__ counts,
    const int* __restrict__ edgeSrc, const u16* __restrict__ xin,
    const u16* __restrict__ Wf,      // this layer's frag weights: [9][8][1024][8]
    const float* __restrict__ bias, const float* __restrict__ invdeg,
    float* __restrict__ outF, u16* __restrict__ outH, int relu, int bc)
{
    __shared__ __align__(16) u16 Af[2][16384];   // 2 x 32 KB double buffer
    __shared__ float sInv[TM];
    __shared__ int sStart[8 * TM], sCnt[8 * TM];

    int t = threadIdx.x;
    int fl = t & 63;
    int wid = t >> 6;            // wave id = n-tile (32 cols each)
    int bid = blockIdx.x;
    int bb, mt0;
    if (bc == 16) {              // XCD swizzle
        bb  = (bid & 7) * 2 + ((bid >> 3) & 1);
        mt0 = bid >> 4;
    } else {
        bb  = bid >> 5;
        mt0 = bid & 31;
    }
    int m0 = mt0 * TM;

    // preload bucket meta: exactly one bucket per thread (8 rel x 64 rows)
    {
        int r = t >> 6, row = t & 63;
        int g = ((bb * RR + r) * NN) + m0 + row;
        sStart[t] = offsets[g];
        sCnt[t]   = counts[g];
    }
    if (t < TM) sInv[t] = invdeg[(size_t)bb * NN + m0 + t];

    const u16* xb = xin + (size_t)bb * NN * DD;
    const int* es = edgeSrc + (size_t)bb * EE;

    // A-build coords: 32 groups of 16 lanes; group handles 2 rows
    int gid = t >> 4;
    int j16 = t & 15;
    int ks0 = j16 >> 1;
    int lh2 = j16 & 1;
    int lh = fl >> 5;

    fx16 acc[2];
    #pragma unroll
    for (int mt = 0; mt < 2; ++mt)
        #pragma unroll
        for (int e = 0; e < 16; ++e) acc[mt][e] = 0.0f;

    __syncthreads();             // meta visible
    build_seg(0, Af[0], sStart, sCnt, es, xb, m0, gid, j16, ks0, lh2);
    __syncthreads();

    for (int seg = 0; seg < 9; ++seg) {
        // build next segment into the other buffer (overlaps this MFMA via
        // wave drift — only one barrier per segment)
        if (seg < 8)
            build_seg(seg + 1, Af[(seg + 1) & 1], sStart, sCnt, es, xb, m0,
                      gid, j16, ks0, lh2);

        if (seg == 8) {
            // normalize aggregation by degree before the root term
            #pragma unroll
            for (int mt = 0; mt < 2; ++mt)
                #pragma unroll
                for (int r = 0; r < 16; ++r) {
                    int rl = mt * 32 + (r & 3) + 8 * (r >> 2) + 4 * lh;
                    acc[mt][r] *= sInv[rl];
                }
        }

        const u16* Wseg = Wf + (size_t)seg * 65536;
        const u16* A = Af[seg & 1];
        #pragma unroll 2
        for (int kt = 0; kt < 8; ++kt) {
            bfx8 bfr[2], af[2][2];
            #pragma unroll
            for (int ks2 = 0; ks2 < 2; ++ks2) {
                int ksA = kt * 2 + ks2;
                bfr[ks2] = *(const bfx8*)(Wseg + (size_t)kt * 8192 + wid * 1024
                                          + ks2 * 512 + fl * 8);
                af[0][ks2] = *(const bfx8*)&A[((0  + ksA) * 64 + ((fl + ksA) & 63)) * 8];
                af[1][ks2] = *(const bfx8*)&A[((16 + ksA) * 64 + ((fl + ksA) & 63)) * 8];
            }
            #pragma unroll
            for (int ks2 = 0; ks2 < 2; ++ks2) {
                acc[0] = __builtin_amdgcn_mfma_f32_32x32x16_bf16(af[0][ks2], bfr[ks2], acc[0], 0, 0, 0);
                acc[1] = __builtin_amdgcn_mfma_f32_32x32x16_bf16(af[1][ks2], bfr[ks2], acc[1], 0, 0, 0);
            }
        }
        __syncthreads();
    }

    // ---- epilogue ----
    int col = wid * 32 + (fl & 31);
    float bv = bias[col];
    #pragma unroll
    for (int mt = 0; mt < 2; ++mt)
        #pragma unroll
        for (int r = 0; r < 16; ++r) {
            int row = m0 + mt * 32 + (r & 3) + 8 * (r >> 2) + 4 * lh;
            float v = acc[mt][r] + bv;
            if (relu) v = fmaxf(v, 0.0f);
            if (WRITE_BF16)
                outH[((size_t)bb * NN + row) * DD + col] = f2bf(v);
            else
                outF[((size_t)bb * NN + row) * DD + col] = v;
        }
}

// ---------------------------------------------------------------------------
extern "C" void kernel_launch(void* const* d_in, const int* in_sizes, int n_in,
                              void* d_out, int out_size, void* d_ws, size_t ws_size,
                              hipStream_t stream)
{
    const int*   nodes = (const int*)d_in[0];
    const int*   edges = (const int*)d_in[1];
    const int*   types = (const int*)d_in[2];
    const float* emb   = (const float*)d_in[3];
    const float* W     = (const float*)d_in[4];
    const float* Wroot = (const float*)d_in[5];
    const float* bias  = (const float*)d_in[6];
    float* out = (float*)d_out;

    const size_t wfElems = (size_t)LL * 9 * 8 * 1024 * 8;
    const size_t fixedBytes = wfElems * sizeof(u16);
    const size_t perBatchBytes =
        2 * (size_t)NN * DD * sizeof(u16) + (size_t)NN * sizeof(float) +
        (3 * (size_t)BUCKETS + EE) * sizeof(int);
    int BC = (int)((ws_size - fixedBytes) / perBatchBytes);
    if (BC > BB) BC = BB;
    if (BC < 1) BC = 1;

    u16* Wf      = (u16*)d_ws;
    u16* x0      = Wf + wfElems;
    u16* x1      = x0 + (size_t)BC * NN * DD;
    float* invdeg = (float*)(x1 + (size_t)BC * NN * DD);
    int* counts  = (int*)(invdeg + (size_t)BC * NN);
    int* offsets = counts + (size_t)BC * BUCKETS;
    int* cursor  = offsets + (size_t)BC * BUCKETS;
    int* edgeSrc = cursor + (size_t)BC * BUCKETS;

    for (int b0 = 0; b0 < BB; b0 += BC) {
        int bc = BB - b0 < BC ? BB - b0 : BC;

        // ---- weight prep + zero counts / gather + count / scan+invdeg / permute
        int zeroBlocks = (bc * BUCKETS / 4 + 255) / 256;
        prep0<<<8 * LL * 9 + zeroBlocks, 256, 0, stream>>>(W, Wroot, Wf, counts, bc);
        prep1<<<bc * 640, 256, 0, stream>>>(nodes, emb, x0, edges, types, counts, b0, bc);
        scan2_k<<<bc, 256, 0, stream>>>(counts, offsets, cursor, invdeg);
        permute_k<<<bc * 128, 256, 0, stream>>>(edges, types, cursor, edgeSrc, b0, bc);

        for (int l = 0; l < LL; ++l) {
            const u16* xin = (l == 0) ? x0 : x1;
            const u16* Wfl = Wf + (size_t)l * 9 * 65536;
            if (l == 0)
                rgcn_fused<1><<<bc * 32, 512, 0, stream>>>(offsets, counts, edgeSrc,
                    xin, Wfl, bias + (size_t)l * DD, invdeg, nullptr, x1, 1, bc);
            else
                rgcn_fused<0><<<bc * 32, 512, 0, stream>>>(offsets, counts, edgeSrc,
                    xin, Wfl, bias + (size_t)l * DD, invdeg,
                    out + (size_t)b0 * NN * DD, nullptr, 0, bc);
        }
    }
}